// Round 6
// baseline (524.016 us; speedup 1.0000x reference)
//
#include <hip/hip_runtime.h>

// B=16384, FEAT=1024, FD=256, M=4 nodes, H1=4x128 (concat->512), H2=1x256, OUT=8.
// Round 6: bit-pure vs round 4 (passed @ absmax 0.0078125 floor).
//  - weights preconverted fp16 (identical rounding to in-staging cast)
//  - feats fp16, normed fp16 (identical: the cast just moved producer-side)
//  - h1, h2, hid fp32; round-4 standalone attention kernels verbatim
//  - middle section chunked x2 over B to fit fp32 buffers in workspace

typedef __attribute__((ext_vector_type(8))) _Float16 f16x8;
typedef __attribute__((ext_vector_type(4))) float f32x4;
typedef _Float16 half_t;

struct P4 { const void* p[4]; };
struct P8 { const void* p[8]; };

__device__ __forceinline__ float sigmoidf_(float x) { return 1.0f / (1.0f + expf(-x)); }
__device__ __forceinline__ float gelu_(float x) {
    return 0.5f * x * (1.0f + erff(x * 0.70710678118654752440f));
}

// ------------- weights fp32 -> fp16, all segments in one dispatch ------------
__device__ const int g_seg_n4[7]   = {65536,65536,65536,65536,32768,32768,16384}; // float4s
__device__ const int g_seg_dofs[7] = {0,262144,524288,786432,1048576,1179648,1310720};

__global__ __launch_bounds__(256)
void cvt_weights(P8 srcs, half_t* __restrict__ dst)
{
    const int seg = blockIdx.y;
    const float* s = (const float*)srcs.p[seg];
    half_t* d = dst + g_seg_dofs[seg];
    const int n4 = g_seg_n4[seg];
    for (int i = blockIdx.x * 256 + threadIdx.x; i < n4; i += gridDim.x * 256) {
        const float4 v = ((const float4*)s)[i];
        union { half_t h[4]; uint2 u; } o;
        o.h[0] = (half_t)v.x; o.h[1] = (half_t)v.y;
        o.h[2] = (half_t)v.z; o.h[3] = (half_t)v.w;
        *(uint2*)(d + (size_t)i * 4) = o.u;
    }
}

// ---- MFMA NT GEMM: C[M,N] = act(A[M,K] @ W[N,K]^T (+bias)) ------------------
// A fp32 (cvt at staging) or fp16; W fp16 preconverted; C fp16 (LDS transpose
// path) or fp32 (direct scattered stores, round-4-proven). BM=BN=128, BK=32,
// 4 waves 2x2, 64x64 per wave. grid.z batches (A, W+z*zWofs, bias, C+z*zofs).
template<int ACT, bool A_F32, bool OUT_F16, bool HAS_BIAS>
__global__ __launch_bounds__(256)
void gemm_u(P4 A4, const half_t* __restrict__ Wbase, int zWofs, P4 b4,
            void* __restrict__ Cv, int K, int lda, int ldc, int zofs)
{
    __shared__ __align__(16) unsigned char smem[32768];
    half_t (*As)[32] = (half_t(*)[32])smem;            // [128][32]
    half_t (*Bs)[32] = (half_t(*)[32])(smem + 8192);   // [128][32]
    half_t (*outT)[128] = (half_t(*)[128])smem;        // [128][128] fp16 epilogue

    const int z = blockIdx.z;
    const half_t* Wh = Wbase + (long)z * zWofs;
    const float* bias = (const float*)b4.p[z];

    const int t = threadIdx.x, lane = t & 63, w = t >> 6;
    const int wr = (w >> 1) << 6, wc = (w & 1) << 6;
    const int fr = lane & 15, fq = lane >> 4, fg = fq << 3;
    const long rowA = (long)blockIdx.y * 128;
    const long colB = (long)blockIdx.x * 128;

    f32x4 acc[4][4] = {};

    for (int k0 = 0; k0 < K; k0 += 32) {
        uint4 bvr[2];
        float4 avr32[4];
        uint4 avr16[2];
        if constexpr (A_F32) {
            const float* A = (const float*)A4.p[z];
            #pragma unroll
            for (int i = 0; i < 4; ++i) {
                const int f = t + i * 256;
                const int r = f >> 3, c = (f & 7) << 2;
                avr32[i] = *(const float4*)(A + (rowA + r) * (long)lda + k0 + c);
            }
        } else {
            const half_t* A = (const half_t*)A4.p[z];
            #pragma unroll
            for (int i = 0; i < 2; ++i) {
                const int s = t + i * 256;
                const int r = s >> 2, c = (s & 3) << 3;
                avr16[i] = *(const uint4*)(A + (rowA + r) * (long)lda + k0 + c);
            }
        }
        #pragma unroll
        for (int i = 0; i < 2; ++i) {
            const int s = t + i * 256;
            const int r = s >> 2, c = (s & 3) << 3;
            bvr[i] = *(const uint4*)(Wh + (colB + r) * (long)K + k0 + c);
        }
        if (k0) __syncthreads();
        if constexpr (A_F32) {
            #pragma unroll
            for (int i = 0; i < 4; ++i) {
                const int f = t + i * 256;
                const int r = f >> 3, c = (f & 7) << 2;
                union { half_t h[4]; uint2 u; } pa;
                pa.h[0] = (half_t)avr32[i].x; pa.h[1] = (half_t)avr32[i].y;
                pa.h[2] = (half_t)avr32[i].z; pa.h[3] = (half_t)avr32[i].w;
                *(uint2*)&As[r][c] = pa.u;
            }
        } else {
            #pragma unroll
            for (int i = 0; i < 2; ++i) {
                const int s = t + i * 256;
                const int r = s >> 2, c = (s & 3) << 3;
                *(uint4*)&As[r][c] = avr16[i];
            }
        }
        #pragma unroll
        for (int i = 0; i < 2; ++i) {
            const int s = t + i * 256;
            const int r = s >> 2, c = (s & 3) << 3;
            *(uint4*)&Bs[r][c] = bvr[i];
        }
        __syncthreads();
        f16x8 af[4], bf[4];
        #pragma unroll
        for (int m = 0; m < 4; ++m) af[m] = *(const f16x8*)&As[wr + m*16 + fr][fg];
        #pragma unroll
        for (int n = 0; n < 4; ++n) bf[n] = *(const f16x8*)&Bs[wc + n*16 + fr][fg];
        #pragma unroll
        for (int m = 0; m < 4; ++m)
            #pragma unroll
            for (int n = 0; n < 4; ++n)
                acc[m][n] = __builtin_amdgcn_mfma_f32_16x16x32_f16(af[m], bf[n], acc[m][n], 0, 0, 0);
    }

    if constexpr (OUT_F16) {
        half_t* Cz = (half_t*)Cv + (long)z * zofs;
        __syncthreads();   // frag reads done; LDS reusable as outT
        float bn[4];
        #pragma unroll
        for (int n = 0; n < 4; ++n)
            bn[n] = HAS_BIAS ? bias[colB + wc + n*16 + fr] : 0.0f;
        #pragma unroll
        for (int m = 0; m < 4; ++m)
            #pragma unroll
            for (int n = 0; n < 4; ++n)
                #pragma unroll
                for (int j = 0; j < 4; ++j) {
                    float x = acc[m][n][j] + bn[n];
                    if (ACT == 1) x = fmaxf(x, 0.0f);
                    outT[wr + m*16 + fq*4 + j][wc + n*16 + fr] = (half_t)x;
                }
        __syncthreads();
        #pragma unroll
        for (int i = 0; i < 8; ++i) {
            const int s = t + i * 256;
            const int r = s >> 4, c = (s & 15) << 3;
            *(uint4*)(Cz + (rowA + r) * (long)ldc + colB + c) = *(const uint4*)&outT[r][c];
        }
    } else {
        float* Cz = (float*)Cv + (long)z * zofs;
        #pragma unroll
        for (int n = 0; n < 4; ++n) {
            const long col = colB + wc + n*16 + fr;
            const float bn = HAS_BIAS ? bias[col] : 0.0f;
            #pragma unroll
            for (int m = 0; m < 4; ++m) {
                const long row0 = rowA + wr + m*16 + fq*4;
                #pragma unroll
                for (int j = 0; j < 4; ++j) {
                    float x = acc[m][n][j] + bn;
                    if (ACT == 1) x = fmaxf(x, 0.0f);
                    Cz[(row0 + j) * (long)ldc + col] = x;
                }
            }
        }
    }
}

// ---------------- GAT1 attention (round-4 verbatim): one wave per (b,h) -----
// h1 layout [Bc,4,512] fp32; in-place update.
__global__ __launch_bounds__(256)
void gat1_attn_kernel(float* __restrict__ h1,
                      const int* __restrict__ missing,
                      const float* __restrict__ attl, const float* __restrict__ attr,
                      const float* __restrict__ bias)
{
    const int gtid = blockIdx.x * 256 + threadIdx.x;
    const int wid  = gtid >> 6;
    const int lane = threadIdx.x & 63;
    const int b = wid >> 2;
    const int h = wid & 3;
    const int cb = h * 128 + lane;
    float* base = h1 + (size_t)b * 2048 + cb;

    float hr[4][2];
    #pragma unroll
    for (int j = 0; j < 4; ++j) { hr[j][0] = base[j*512]; hr[j][1] = base[j*512 + 64]; }
    const float al0 = attl[cb], al1 = attl[cb+64];
    const float ar0 = attr[cb], ar1 = attr[cb+64];

    float red[24];
    #pragma unroll
    for (int i = 0; i < 4; ++i)
        #pragma unroll
        for (int j = 0; j < 4; ++j)
            red[i*4+j] = hr[i][0]*hr[j][0] + hr[i][1]*hr[j][1];
    #pragma unroll
    for (int j = 0; j < 4; ++j) {
        red[16+j] = hr[j][0]*al0 + hr[j][1]*al1;
        red[20+j] = hr[j][0]*ar0 + hr[j][1]*ar1;
    }
    #pragma unroll
    for (int m = 1; m < 64; m <<= 1)
        #pragma unroll
        for (int r = 0; r < 24; ++r)
            red[r] += __shfl_xor(red[r], m, 64);

    const int miss = missing[b];
    bool pres[4];
    #pragma unroll
    for (int mm = 0; mm < 4; ++mm) pres[mm] = (miss != mm + 1);

    float attn[4][4];
    #pragma unroll
    for (int i = 0; i < 4; ++i) {
        float av[4]; float mx = -3.4e38f;
        #pragma unroll
        for (int j = 0; j < 4; ++j) {
            const bool mk = (i == j) || (pres[i] && pres[j]);
            float v = (red[20+i] + red[16+j]) * sigmoidf_(red[i*4+j]);
            v = (v >= 0.0f) ? v : 0.2f * v;
            av[j] = mk ? v : -1e30f;
            mx = fmaxf(mx, av[j]);
        }
        float den = 0.0f;
        #pragma unroll
        for (int j = 0; j < 4; ++j) { av[j] = expf(av[j] - mx); den += av[j]; }
        const float inv = 1.0f / den;
        #pragma unroll
        for (int j = 0; j < 4; ++j) attn[i][j] = av[j] * inv;
    }

    const float b0 = bias[cb], b1 = bias[cb+64];
    #pragma unroll
    for (int i = 0; i < 4; ++i) {
        float o0 = b0, o1 = b1;
        #pragma unroll
        for (int j = 0; j < 4; ++j) { o0 += attn[i][j]*hr[j][0]; o1 += attn[i][j]*hr[j][1]; }
        base[i*512]      = gelu_(o0);
        base[i*512 + 64] = gelu_(o1);
    }
}

// ------- GAT2 attention + pool + LayerNorm (round-4 verbatim math); ----------
// h2 [Bc,4,256] fp32 -> normed fp16 (cast identical to head1's staging cast).
__global__ __launch_bounds__(256)
void gat2_attn_kernel(const float* __restrict__ h2,
                      const int* __restrict__ missing,
                      const float* __restrict__ attl, const float* __restrict__ attr,
                      const float* __restrict__ bias,
                      const float* __restrict__ lng, const float* __restrict__ lnb,
                      half_t* __restrict__ normed)
{
    const int gtid = blockIdx.x * 256 + threadIdx.x;
    const int b = gtid >> 6;
    const int lane = threadIdx.x & 63;
    const float4* hp = (const float4*)(h2 + (size_t)b * 1024);

    float4 hr[4];
    #pragma unroll
    for (int j = 0; j < 4; ++j) hr[j] = hp[j*64 + lane];
    const float4 al = ((const float4*)attl)[lane];
    const float4 ar = ((const float4*)attr)[lane];

    float red[24];
    #pragma unroll
    for (int i = 0; i < 4; ++i)
        #pragma unroll
        for (int j = 0; j < 4; ++j)
            red[i*4+j] = hr[i].x*hr[j].x + hr[i].y*hr[j].y + hr[i].z*hr[j].z + hr[i].w*hr[j].w;
    #pragma unroll
    for (int j = 0; j < 4; ++j) {
        red[16+j] = hr[j].x*al.x + hr[j].y*al.y + hr[j].z*al.z + hr[j].w*al.w;
        red[20+j] = hr[j].x*ar.x + hr[j].y*ar.y + hr[j].z*ar.z + hr[j].w*ar.w;
    }
    #pragma unroll
    for (int m = 1; m < 64; m <<= 1)
        #pragma unroll
        for (int r = 0; r < 24; ++r)
            red[r] += __shfl_xor(red[r], m, 64);

    const int miss = missing[b];
    bool pres[4];
    #pragma unroll
    for (int mm = 0; mm < 4; ++mm) pres[mm] = (miss != mm + 1);

    float wsum[4] = {0.f, 0.f, 0.f, 0.f};
    #pragma unroll
    for (int i = 0; i < 4; ++i) {
        float av[4]; float mx = -3.4e38f;
        #pragma unroll
        for (int j = 0; j < 4; ++j) {
            const bool mk = (i == j) || (pres[i] && pres[j]);
            float v = (red[20+i] + red[16+j]) * sigmoidf_(red[i*4+j]);
            v = (v >= 0.0f) ? v : 0.2f * v;
            av[j] = mk ? v : -1e30f;
            mx = fmaxf(mx, av[j]);
        }
        float den = 0.0f;
        #pragma unroll
        for (int j = 0; j < 4; ++j) { av[j] = expf(av[j] - mx); den += av[j]; }
        const float inv = 0.25f / den;
        #pragma unroll
        for (int j = 0; j < 4; ++j) wsum[j] += av[j] * inv;
    }

    const float4 bv = ((const float4*)bias)[lane];
    float pooled[4] = {bv.x, bv.y, bv.z, bv.w};
    #pragma unroll
    for (int j = 0; j < 4; ++j) {
        pooled[0] += wsum[j] * hr[j].x;
        pooled[1] += wsum[j] * hr[j].y;
        pooled[2] += wsum[j] * hr[j].z;
        pooled[3] += wsum[j] * hr[j].w;
    }

    float s1 = pooled[0] + pooled[1] + pooled[2] + pooled[3];
    float s2 = pooled[0]*pooled[0] + pooled[1]*pooled[1] + pooled[2]*pooled[2] + pooled[3]*pooled[3];
    #pragma unroll
    for (int m = 1; m < 64; m <<= 1) {
        s1 += __shfl_xor(s1, m, 64);
        s2 += __shfl_xor(s2, m, 64);
    }
    const float mu   = s1 * (1.0f / 256.0f);
    const float var  = s2 * (1.0f / 256.0f) - mu * mu;
    const float rstd = rsqrtf(var + 1e-5f);
    const float4 g  = ((const float4*)lng)[lane];
    const float4 bb = ((const float4*)lnb)[lane];
    union { half_t h[4]; uint2 u; } o;
    o.h[0] = (half_t)((pooled[0] - mu) * rstd * g.x + bb.x);
    o.h[1] = (half_t)((pooled[1] - mu) * rstd * g.y + bb.y);
    o.h[2] = (half_t)((pooled[2] - mu) * rstd * g.z + bb.z);
    o.h[3] = (half_t)((pooled[3] - mu) * rstd * g.w + bb.w);
    *(uint2*)(normed + (size_t)b * 256 + lane * 4) = o.u;
}

// ---------------- head2 (round-4 verbatim): fp32 hid ------------------------
__global__ __launch_bounds__(256)
void head2_kernel(const float* __restrict__ hid, const float* __restrict__ W2,
                  const float* __restrict__ b2, float* __restrict__ out)
{
    const int t = blockIdx.x * 256 + threadIdx.x;
    const int b = t >> 3, o = t & 7;
    const float4* hp = (const float4*)(hid + (size_t)b * 256);
    const float4* wp = (const float4*)(W2 + o * 256);
    float acc = b2[o];
    #pragma unroll 8
    for (int c = 0; c < 64; ++c) {
        const float4 hv = hp[c], wv = wp[c];
        acc += hv.x*wv.x + hv.y*wv.y + hv.z*wv.z + hv.w*wv.w;
    }
    out[t] = acc;
}

// ---------------- launch ----------------------------------------------------
extern "C" void kernel_launch(void* const* d_in, const int* in_sizes, int n_in,
                              void* d_out, int out_size, void* d_ws, size_t ws_size,
                              hipStream_t stream)
{
    (void)in_sizes; (void)n_in; (void)out_size; (void)ws_size;
    const int*   miss  = (const int*)d_in[4];
    const float* g1_al = (const float*)d_in[14];
    const float* g1_ar = (const float*)d_in[15];
    const float* g1_b  = (const float*)d_in[16];
    const float* g2_al = (const float*)d_in[18];
    const float* g2_ar = (const float*)d_in[19];
    const float* g2_b  = (const float*)d_in[20];
    const float* ln_g  = (const float*)d_in[21];
    const float* ln_b  = (const float*)d_in[22];
    const float* h_W2  = (const float*)d_in[25];
    const float* h_b2  = (const float*)d_in[26];
    float* out = (float*)d_out;

    // workspace (byte offsets, 156 MB total):
    //   wf16   @   0 MB (2.75 MB weights fp16)
    //   feats  @   4 MB  fp16 [16384,1024]   (32 MB)
    //   h1     @  36 MB  fp32 [32768,512] chunk (64 MB)
    //   h2     @ 100 MB  fp32 [32768,256] chunk (32 MB)
    //   normed @ 132 MB  fp16 [16384,256]    (8 MB)
    //   hid    @ 140 MB  fp32 [16384,256]   (16 MB)
    char* base = (char*)d_ws;
    half_t* wf16   = (half_t*)base;
    half_t* feats  = (half_t*)(base + (4ll  << 20));
    float*  h1     = (float*) (base + (36ll << 20));
    float*  h2     = (float*) (base + (100ll<< 20));
    half_t* normed = (half_t*)(base + (132ll<< 20));
    float*  hid    = (float*) (base + (140ll<< 20));

    const dim3 blk(256);

    P8 wsrc = {{d_in[5], d_in[7], d_in[9], d_in[11], d_in[13], d_in[17], d_in[23], d_in[23]}};
    cvt_weights<<<dim3(64, 7), blk, 0, stream>>>(wsrc, wf16);

    // 1) projections (z-batched): feats[B, 4x256] fp16
    P4 Xs  = {{d_in[0], d_in[1], d_in[2], d_in[3]}};
    P4 bms = {{d_in[6], d_in[8], d_in[10], d_in[12]}};
    gemm_u<0, true, true, true><<<dim3(2, 128, 4), blk, 0, stream>>>(
        Xs, wf16, 262144, bms, feats, /*K=*/1024, /*lda=*/1024, /*ldc=*/1024, /*zofs=*/256);

    P4 NUL = {{nullptr, nullptr, nullptr, nullptr}};

    // 2) middle section, 2 chunks of 8192 samples (32768 node-rows)
    for (int c = 0; c < 2; ++c) {
        const long roff = (long)c * 32768;   // node rows
        const int  soff = c * 8192;          // samples

        // gat1 linear: h1[32768,512] fp32 = feats_chunk @ g1_W^T
        P4 Ac = {{feats + roff * 256, nullptr, nullptr, nullptr}};
        gemm_u<0, false, false, false><<<dim3(4, 256, 1), blk, 0, stream>>>(
            Ac, wf16 + 1048576, 0, NUL, h1, 256, 256, 512, 0);

        // gat1 attention + bias + gelu (in-place fp32)
        gat1_attn_kernel<<<dim3(8192), blk, 0, stream>>>(
            h1, miss + soff, g1_al, g1_ar, g1_b);

        // gat2 linear: h2[32768,256] fp32 = h1 @ g2_W^T  (fp32 A, cvt at staging)
        P4 Hc = {{h1, nullptr, nullptr, nullptr}};
        gemm_u<0, true, false, false><<<dim3(2, 256, 1), blk, 0, stream>>>(
            Hc, wf16 + 1179648, 0, NUL, h2, 512, 512, 256, 0);

        // gat2 attention + pool + layernorm -> normed chunk fp16
        gat2_attn_kernel<<<dim3(2048), blk, 0, stream>>>(
            h2, miss + soff, g2_al, g2_ar, g2_b, ln_g, ln_b,
            normed + (size_t)soff * 256);
    }

    // 3) head1: hid fp32 = relu(normed @ h_W1^T + h_b1)
    P4 N4  = {{normed, nullptr, nullptr, nullptr}};
    P4 HB1 = {{d_in[24], nullptr, nullptr, nullptr}};
    gemm_u<1, false, false, true><<<dim3(2, 128, 1), blk, 0, stream>>>(
        N4, wf16 + 1310720, 0, HB1, hid, 256, 256, 256, 0);

    // 4) head2: out[16384,8] fp32
    head2_kernel<<<dim3(512), blk, 0, stream>>>(hid, h_W2, h_b2, out);
}

// Round 9
// 444.521 us; speedup vs baseline: 1.1788x; 1.1788x over previous
//
#include <hip/hip_runtime.h>

// B=16384, FEAT=1024, FD=256, M=4 nodes, H1=4x128 (concat->512), H2=1x256, OUT=8.
// Round 9: round-4 structure verbatim (best passing, 422us) with ONE change:
// BM=64 tiles for proj/gat1-lin/gat2-lin (occupancy 2->~8 blocks/CU).
// Math bit-identical to round 4 (same per-element k-accumulation chain).

typedef __attribute__((ext_vector_type(8))) _Float16 f16x8;
typedef __attribute__((ext_vector_type(4))) float f32x4;

struct P4 { const float* p[4]; };

__device__ __forceinline__ float sigmoidf_(float x) { return 1.0f / (1.0f + expf(-x)); }
__device__ __forceinline__ float gelu_(float x) {
    return 0.5f * x * (1.0f + erff(x * 0.70710678118654752440f));
}

// ---------------- fp16-MFMA NT GEMM: C[M,N] = act(A[M,K] @ Bw[N,K]^T + bias) -
// fp32 in memory, converted to fp16 during LDS staging; fp32 accumulate.
// BM templated (128 or 64), BN=128, BK=32, 256 threads = 4 waves (2x2);
// wave tile (BM/2) x 64. grid.z batches (A,W,bias) triples writing C + z*zofs.
template<int BM, int ACT, bool HAS_BIAS>
__global__ __launch_bounds__(256)
void gemm_nt_mfma(P4 A4, P4 W4, P4 b4, float* __restrict__ C,
                  int K, int lda, int ldc, int zofs)
{
    constexpr int WR = BM / 2;      // wave row span
    constexpr int MR = WR / 16;     // acc row-fragments per wave
    constexpr int NA = BM / 32;     // A staging float4-iters per thread
    __shared__ __align__(16) _Float16 As[BM][32];
    __shared__ __align__(16) _Float16 Bs[128][32];
    const int z = blockIdx.z;
    const float* __restrict__ A    = A4.p[z];
    const float* __restrict__ Bw   = W4.p[z];
    const float* __restrict__ bias = b4.p[z];
    float* __restrict__ Cz = C + (long)z * zofs;

    const int t    = threadIdx.x;
    const int lane = t & 63;
    const int w    = t >> 6;
    const int wr   = (w >> 1) * WR;     // wave row base
    const int wc   = (w & 1) << 6;      // wave col base (0/64)
    const long rowA = (long)blockIdx.y * BM;
    const long colB = (long)blockIdx.x * 128;

    f32x4 acc[MR][4] = {};

    for (int k0 = 0; k0 < K; k0 += 32) {
        // ---- stage BMx32 A and 128x32 Bw (fp32 -> fp16) ----
        float4 areg[NA], breg[4];
        #pragma unroll
        for (int i = 0; i < NA; ++i) {
            const int f = t + i * 256;          // float4 slot
            const int r = f >> 3;               // row 0..BM-1
            const int c = (f & 7) << 2;         // col 0,4,..28
            areg[i] = *(const float4*)(A + (rowA + r) * (long)lda + k0 + c);
        }
        #pragma unroll
        for (int i = 0; i < 4; ++i) {
            const int f = t + i * 256;
            const int r = f >> 3;
            const int c = (f & 7) << 2;
            breg[i] = *(const float4*)(Bw + (colB + r) * (long)K + k0 + c);
        }
        if (k0) __syncthreads();
        #pragma unroll
        for (int i = 0; i < NA; ++i) {
            const int f = t + i * 256;
            const int r = f >> 3;
            const int c = (f & 7) << 2;
            union { _Float16 h[4]; uint2 u; } pa;
            pa.h[0] = (_Float16)areg[i].x; pa.h[1] = (_Float16)areg[i].y;
            pa.h[2] = (_Float16)areg[i].z; pa.h[3] = (_Float16)areg[i].w;
            *(uint2*)&As[r][c] = pa.u;
        }
        #pragma unroll
        for (int i = 0; i < 4; ++i) {
            const int f = t + i * 256;
            const int r = f >> 3;
            const int c = (f & 7) << 2;
            union { _Float16 h[4]; uint2 u; } pb;
            pb.h[0] = (_Float16)breg[i].x; pb.h[1] = (_Float16)breg[i].y;
            pb.h[2] = (_Float16)breg[i].z; pb.h[3] = (_Float16)breg[i].w;
            *(uint2*)&Bs[r][c] = pb.u;
        }
        __syncthreads();

        // ---- fragments + MFMA ----
        const int fr = lane & 15;
        const int fg = (lane >> 4) << 3;
        f16x8 af[MR], bf[4];
        #pragma unroll
        for (int m = 0; m < MR; ++m) af[m] = *(const f16x8*)&As[wr + m*16 + fr][fg];
        #pragma unroll
        for (int n = 0; n < 4; ++n) bf[n] = *(const f16x8*)&Bs[wc + n*16 + fr][fg];
        #pragma unroll
        for (int m = 0; m < MR; ++m)
            #pragma unroll
            for (int n = 0; n < 4; ++n)
                acc[m][n] = __builtin_amdgcn_mfma_f32_16x16x32_f16(af[m], bf[n], acc[m][n], 0, 0, 0);
        __syncthreads();
    }

    // ---- epilogue: C/D layout col = lane&15, row = (lane>>4)*4 + j ----
    const int fr = lane & 15;
    const int fq = lane >> 4;
    #pragma unroll
    for (int n = 0; n < 4; ++n) {
        const long col = colB + wc + n*16 + fr;
        const float bn = HAS_BIAS ? bias[col] : 0.0f;
        #pragma unroll
        for (int m = 0; m < MR; ++m) {
            const long row0 = rowA + wr + m*16 + fq*4;
            #pragma unroll
            for (int j = 0; j < 4; ++j) {
                float x = acc[m][n][j] + bn;
                if (ACT == 1) x = fmaxf(x, 0.0f);
                Cz[(row0 + j) * (long)ldc + col] = x;
            }
        }
    }
}

// ---------------- GAT1 attention (round-4 verbatim): one wave per (b,h) -----
// h1 layout [B,4,512]; in-place (each (b,h) slice owned by exactly one wave).
__global__ __launch_bounds__(256)
void gat1_attn_kernel(float* __restrict__ h1,
                      const int* __restrict__ missing,
                      const float* __restrict__ attl, const float* __restrict__ attr,
                      const float* __restrict__ bias)
{
    const int gtid = blockIdx.x * 256 + threadIdx.x;
    const int wid  = gtid >> 6;
    const int lane = threadIdx.x & 63;
    const int b = wid >> 2;
    const int h = wid & 3;
    const int cb = h * 128 + lane;
    float* base = h1 + (size_t)b * 2048 + cb;

    float hr[4][2];
    #pragma unroll
    for (int j = 0; j < 4; ++j) { hr[j][0] = base[j*512]; hr[j][1] = base[j*512 + 64]; }
    const float al0 = attl[cb], al1 = attl[cb+64];
    const float ar0 = attr[cb], ar1 = attr[cb+64];

    float red[24];
    #pragma unroll
    for (int i = 0; i < 4; ++i)
        #pragma unroll
        for (int j = 0; j < 4; ++j)
            red[i*4+j] = hr[i][0]*hr[j][0] + hr[i][1]*hr[j][1];
    #pragma unroll
    for (int j = 0; j < 4; ++j) {
        red[16+j] = hr[j][0]*al0 + hr[j][1]*al1;
        red[20+j] = hr[j][0]*ar0 + hr[j][1]*ar1;
    }
    #pragma unroll
    for (int m = 1; m < 64; m <<= 1)
        #pragma unroll
        for (int r = 0; r < 24; ++r)
            red[r] += __shfl_xor(red[r], m, 64);

    const int miss = missing[b];
    bool pres[4];
    #pragma unroll
    for (int mm = 0; mm < 4; ++mm) pres[mm] = (miss != mm + 1);

    float attn[4][4];
    #pragma unroll
    for (int i = 0; i < 4; ++i) {
        float av[4]; float mx = -3.4e38f;
        #pragma unroll
        for (int j = 0; j < 4; ++j) {
            const bool mk = (i == j) || (pres[i] && pres[j]);
            float v = (red[20+i] + red[16+j]) * sigmoidf_(red[i*4+j]);
            v = (v >= 0.0f) ? v : 0.2f * v;
            av[j] = mk ? v : -1e30f;
            mx = fmaxf(mx, av[j]);
        }
        float den = 0.0f;
        #pragma unroll
        for (int j = 0; j < 4; ++j) { av[j] = expf(av[j] - mx); den += av[j]; }
        const float inv = 1.0f / den;
        #pragma unroll
        for (int j = 0; j < 4; ++j) attn[i][j] = av[j] * inv;
    }

    const float b0 = bias[cb], b1 = bias[cb+64];
    #pragma unroll
    for (int i = 0; i < 4; ++i) {
        float o0 = b0, o1 = b1;
        #pragma unroll
        for (int j = 0; j < 4; ++j) { o0 += attn[i][j]*hr[j][0]; o1 += attn[i][j]*hr[j][1]; }
        base[i*512]      = gelu_(o0);
        base[i*512 + 64] = gelu_(o1);
    }
}

// ------- GAT2 attention + node-mean pool + LayerNorm (round-4 verbatim) ------
__global__ __launch_bounds__(256)
void gat2_attn_kernel(const float* __restrict__ h2,
                      const int* __restrict__ missing,
                      const float* __restrict__ attl, const float* __restrict__ attr,
                      const float* __restrict__ bias,
                      const float* __restrict__ lng, const float* __restrict__ lnb,
                      float* __restrict__ normed)
{
    const int gtid = blockIdx.x * 256 + threadIdx.x;
    const int b = gtid >> 6;
    const int lane = threadIdx.x & 63;
    const float4* hp = (const float4*)(h2 + (size_t)b * 1024);

    float4 hr[4];
    #pragma unroll
    for (int j = 0; j < 4; ++j) hr[j] = hp[j*64 + lane];
    const float4 al = ((const float4*)attl)[lane];
    const float4 ar = ((const float4*)attr)[lane];

    float red[24];
    #pragma unroll
    for (int i = 0; i < 4; ++i)
        #pragma unroll
        for (int j = 0; j < 4; ++j)
            red[i*4+j] = hr[i].x*hr[j].x + hr[i].y*hr[j].y + hr[i].z*hr[j].z + hr[i].w*hr[j].w;
    #pragma unroll
    for (int j = 0; j < 4; ++j) {
        red[16+j] = hr[j].x*al.x + hr[j].y*al.y + hr[j].z*al.z + hr[j].w*al.w;
        red[20+j] = hr[j].x*ar.x + hr[j].y*ar.y + hr[j].z*ar.z + hr[j].w*ar.w;
    }
    #pragma unroll
    for (int m = 1; m < 64; m <<= 1)
        #pragma unroll
        for (int r = 0; r < 24; ++r)
            red[r] += __shfl_xor(red[r], m, 64);

    const int miss = missing[b];
    bool pres[4];
    #pragma unroll
    for (int mm = 0; mm < 4; ++mm) pres[mm] = (miss != mm + 1);

    float wsum[4] = {0.f, 0.f, 0.f, 0.f};
    #pragma unroll
    for (int i = 0; i < 4; ++i) {
        float av[4]; float mx = -3.4e38f;
        #pragma unroll
        for (int j = 0; j < 4; ++j) {
            const bool mk = (i == j) || (pres[i] && pres[j]);
            float v = (red[20+i] + red[16+j]) * sigmoidf_(red[i*4+j]);
            v = (v >= 0.0f) ? v : 0.2f * v;
            av[j] = mk ? v : -1e30f;
            mx = fmaxf(mx, av[j]);
        }
        float den = 0.0f;
        #pragma unroll
        for (int j = 0; j < 4; ++j) { av[j] = expf(av[j] - mx); den += av[j]; }
        const float inv = 0.25f / den;
        #pragma unroll
        for (int j = 0; j < 4; ++j) wsum[j] += av[j] * inv;
    }

    const float4 bv = ((const float4*)bias)[lane];
    float pooled[4] = {bv.x, bv.y, bv.z, bv.w};
    #pragma unroll
    for (int j = 0; j < 4; ++j) {
        pooled[0] += wsum[j] * hr[j].x;
        pooled[1] += wsum[j] * hr[j].y;
        pooled[2] += wsum[j] * hr[j].z;
        pooled[3] += wsum[j] * hr[j].w;
    }

    float s1 = pooled[0] + pooled[1] + pooled[2] + pooled[3];
    float s2 = pooled[0]*pooled[0] + pooled[1]*pooled[1] + pooled[2]*pooled[2] + pooled[3]*pooled[3];
    #pragma unroll
    for (int m = 1; m < 64; m <<= 1) {
        s1 += __shfl_xor(s1, m, 64);
        s2 += __shfl_xor(s2, m, 64);
    }
    const float mu   = s1 * (1.0f / 256.0f);
    const float var  = s2 * (1.0f / 256.0f) - mu * mu;
    const float rstd = rsqrtf(var + 1e-5f);
    const float4 g  = ((const float4*)lng)[lane];
    const float4 bb = ((const float4*)lnb)[lane];
    float4 o;
    o.x = (pooled[0] - mu) * rstd * g.x + bb.x;
    o.y = (pooled[1] - mu) * rstd * g.y + bb.y;
    o.z = (pooled[2] - mu) * rstd * g.z + bb.z;
    o.w = (pooled[3] - mu) * rstd * g.w + bb.w;
    ((float4*)normed)[(size_t)b * 64 + lane] = o;
}

// ---------------- head2 (round-4 verbatim) ----------------------------------
__global__ __launch_bounds__(256)
void head2_kernel(const float* __restrict__ hid, const float* __restrict__ W2,
                  const float* __restrict__ b2, float* __restrict__ out)
{
    const int t = blockIdx.x * 256 + threadIdx.x;
    const int b = t >> 3, o = t & 7;
    const float4* hp = (const float4*)(hid + (size_t)b * 256);
    const float4* wp = (const float4*)(W2 + o * 256);
    float acc = b2[o];
    #pragma unroll 8
    for (int c = 0; c < 64; ++c) {
        const float4 hv = hp[c], wv = wp[c];
        acc += hv.x*wv.x + hv.y*wv.y + hv.z*wv.z + hv.w*wv.w;
    }
    out[t] = acc;
}

// ---------------- launch ----------------------------------------------------
extern "C" void kernel_launch(void* const* d_in, const int* in_sizes, int n_in,
                              void* d_out, int out_size, void* d_ws, size_t ws_size,
                              hipStream_t stream)
{
    (void)in_sizes; (void)n_in; (void)out_size; (void)ws_size;
    const float* X0 = (const float*)d_in[0];
    const float* X1 = (const float*)d_in[1];
    const float* X2 = (const float*)d_in[2];
    const float* X3 = (const float*)d_in[3];
    const int*   miss  = (const int*)d_in[4];
    const float* g1_W  = (const float*)d_in[13];
    const float* g1_al = (const float*)d_in[14];
    const float* g1_ar = (const float*)d_in[15];
    const float* g1_b  = (const float*)d_in[16];
    const float* g2_W  = (const float*)d_in[17];
    const float* g2_al = (const float*)d_in[18];
    const float* g2_ar = (const float*)d_in[19];
    const float* g2_b  = (const float*)d_in[20];
    const float* ln_g  = (const float*)d_in[21];
    const float* ln_b  = (const float*)d_in[22];
    const float* h_W1  = (const float*)d_in[23];
    const float* h_b1  = (const float*)d_in[24];
    const float* h_W2  = (const float*)d_in[25];
    const float* h_b2  = (const float*)d_in[26];
    float* out = (float*)d_out;

    // workspace (fp32 elems), round-4 verbatim:
    //   feats [16384,1024] @0 (reused as h2); h1 [65536,512] @16777216
    //   (reused as normed [16384,256] + hid [16384,256])
    float* ws     = (float*)d_ws;
    float* feats  = ws;
    float* h1     = ws + 16777216;
    float* h2     = ws;
    float* normed = ws + 16777216;
    float* hid    = normed + 4194304;

    const dim3 blk(256);

    P4 Xs  = {{X0, X1, X2, X3}};
    P4 Wms = {{(const float*)d_in[5], (const float*)d_in[7],
               (const float*)d_in[9], (const float*)d_in[11]}};
    P4 bms = {{(const float*)d_in[6], (const float*)d_in[8],
               (const float*)d_in[10], (const float*)d_in[12]}};
    P4 F4  = {{feats, feats, feats, feats}};
    P4 G1W = {{g1_W, g1_W, g1_W, g1_W}};
    P4 H14 = {{h1, h1, h1, h1}};
    P4 G2W = {{g2_W, g2_W, g2_W, g2_W}};
    P4 N4  = {{normed, normed, normed, normed}};
    P4 HW1 = {{h_W1, h_W1, h_W1, h_W1}};
    P4 HB1 = {{h_b1, h_b1, h_b1, h_b1}};
    P4 NUL = {{nullptr, nullptr, nullptr, nullptr}};

    // 1) per-modality projections (z-batched), BM=64: feats[B,4,256]
    gemm_nt_mfma<64, 0, true><<<dim3(2, 256, 4), blk, 0, stream>>>(
        Xs, Wms, bms, feats, /*K=*/1024, /*lda=*/1024, /*ldc=*/1024, /*zofs=*/256);

    // 2) gat1 linear, BM=64: h1[65536,512] = feats @ g1_W^T
    gemm_nt_mfma<64, 0, false><<<dim3(4, 1024, 1), blk, 0, stream>>>(
        F4, G1W, NUL, h1, 256, 256, 512, 0);

    // 3) gat1 attention + bias + gelu (in-place on h1)
    gat1_attn_kernel<<<dim3(16384), blk, 0, stream>>>(h1, miss, g1_al, g1_ar, g1_b);

    // 4) gat2 linear, BM=64: h2[65536,256] = x1 @ g2_W^T
    gemm_nt_mfma<64, 0, false><<<dim3(2, 1024, 1), blk, 0, stream>>>(
        H14, G2W, NUL, h2, 512, 512, 256, 0);

    // 5) gat2 attention + pool + layernorm -> normed[16384,256]
    gat2_attn_kernel<<<dim3(4096), blk, 0, stream>>>(
        h2, miss, g2_al, g2_ar, g2_b, ln_g, ln_b, normed);

    // 6) head1 (BM=128, round-4 verbatim): hid = relu(normed @ h_W1^T + h_b1)
    gemm_nt_mfma<128, 1, true><<<dim3(2, 128, 1), blk, 0, stream>>>(
        N4, HW1, HB1, hid, 256, 256, 256, 0);

    // 7) head2: out[16384,8]
    head2_kernel<<<dim3(512), blk, 0, stream>>>(hid, h_W2, h_b2, out);
}

// Round 10
// 411.825 us; speedup vs baseline: 1.2724x; 1.0794x over previous
//
#include <hip/hip_runtime.h>

// B=16384, FEAT=1024, FD=256, M=4 nodes, H1=4x128 (concat->512), H2=1x256, OUT=8.
// Round 10: round-4 verbatim (best passing, 422us) + ONE change: software-
// pipelined staging in the GEMM (prefetch next K-tile's global loads before
// the MFMA block). Math bit-identical to round 4.

typedef __attribute__((ext_vector_type(8))) _Float16 f16x8;
typedef __attribute__((ext_vector_type(4))) float f32x4;

struct P4 { const float* p[4]; };

__device__ __forceinline__ float sigmoidf_(float x) { return 1.0f / (1.0f + expf(-x)); }
__device__ __forceinline__ float gelu_(float x) {
    return 0.5f * x * (1.0f + erff(x * 0.70710678118654752440f));
}

// ---------------- fp16-MFMA NT GEMM: C[M,N] = act(A[M,K] @ Bw[N,K]^T + bias) -
// fp32 in memory, converted to fp16 during LDS staging; fp32 accumulate.
// BM=BN=128, BK=32, 256 threads = 4 waves (2x2), each wave owns 64x64 out.
// Software pipeline: global loads for tile k+1 issued before MFMA on tile k.
template<int ACT, bool HAS_BIAS>
__global__ __launch_bounds__(256)
void gemm_nt_mfma(P4 A4, P4 W4, P4 b4, float* __restrict__ C,
                  int K, int lda, int ldc, int zofs)
{
    __shared__ __align__(16) _Float16 As[128][32];
    __shared__ __align__(16) _Float16 Bs[128][32];
    const int z = blockIdx.z;
    const float* __restrict__ A    = A4.p[z];
    const float* __restrict__ Bw   = W4.p[z];
    const float* __restrict__ bias = b4.p[z];
    float* __restrict__ Cz = C + (long)z * zofs;

    const int t    = threadIdx.x;
    const int lane = t & 63;
    const int w    = t >> 6;
    const int wr   = (w >> 1) << 6;     // wave row base (0/64)
    const int wc   = (w & 1) << 6;      // wave col base (0/64)
    const long rowA = (long)blockIdx.y * 128;
    const long colB = (long)blockIdx.x * 128;

    // per-thread staging addresses: slot f = t + i*256 -> row f>>3, col (f&7)*4
    const float* Apt[4];
    const float* Bpt[4];
    #pragma unroll
    for (int i = 0; i < 4; ++i) {
        const int f = t + i * 256;
        const int r = f >> 3;
        const int c = (f & 7) << 2;
        Apt[i] = A  + (rowA + r) * (long)lda + c;
        Bpt[i] = Bw + (colB + r) * (long)K   + c;
    }

    f32x4 acc[4][4] = {};

    // prologue: load tile 0
    float4 areg[4], breg[4];
    #pragma unroll
    for (int i = 0; i < 4; ++i) {
        areg[i] = *(const float4*)(Apt[i]);
        breg[i] = *(const float4*)(Bpt[i]);
    }

    for (int k0 = 0; k0 < K; k0 += 32) {
        if (k0) __syncthreads();            // prev iter's frag reads complete
        // ---- store current tile to LDS (fp32 -> fp16) ----
        #pragma unroll
        for (int i = 0; i < 4; ++i) {
            const int f = t + i * 256;
            const int r = f >> 3;
            const int c = (f & 7) << 2;
            union { _Float16 h[4]; uint2 u; } pa, pb;
            pa.h[0] = (_Float16)areg[i].x; pa.h[1] = (_Float16)areg[i].y;
            pa.h[2] = (_Float16)areg[i].z; pa.h[3] = (_Float16)areg[i].w;
            pb.h[0] = (_Float16)breg[i].x; pb.h[1] = (_Float16)breg[i].y;
            pb.h[2] = (_Float16)breg[i].z; pb.h[3] = (_Float16)breg[i].w;
            *(uint2*)&As[r][c] = pa.u;
            *(uint2*)&Bs[r][c] = pb.u;
        }
        __syncthreads();

        // ---- prefetch next tile (latency hides under MFMA below) ----
        const int kn = k0 + 32;
        if (kn < K) {
            #pragma unroll
            for (int i = 0; i < 4; ++i) {
                areg[i] = *(const float4*)(Apt[i] + kn);
                breg[i] = *(const float4*)(Bpt[i] + kn);
            }
        }

        // ---- fragments + MFMA ----
        const int fr = lane & 15;
        const int fg = (lane >> 4) << 3;
        f16x8 af[4], bf[4];
        #pragma unroll
        for (int m = 0; m < 4; ++m) af[m] = *(const f16x8*)&As[wr + m*16 + fr][fg];
        #pragma unroll
        for (int n = 0; n < 4; ++n) bf[n] = *(const f16x8*)&Bs[wc + n*16 + fr][fg];
        #pragma unroll
        for (int m = 0; m < 4; ++m)
            #pragma unroll
            for (int n = 0; n < 4; ++n)
                acc[m][n] = __builtin_amdgcn_mfma_f32_16x16x32_f16(af[m], bf[n], acc[m][n], 0, 0, 0);
    }

    // ---- epilogue: C/D layout col = lane&15, row = (lane>>4)*4 + j ----
    const int fr = lane & 15;
    const int fq = lane >> 4;
    #pragma unroll
    for (int n = 0; n < 4; ++n) {
        const long col = colB + wc + n*16 + fr;
        const float bn = HAS_BIAS ? bias[col] : 0.0f;
        #pragma unroll
        for (int m = 0; m < 4; ++m) {
            const long row0 = rowA + wr + m*16 + fq*4;
            #pragma unroll
            for (int j = 0; j < 4; ++j) {
                float x = acc[m][n][j] + bn;
                if (ACT == 1) x = fmaxf(x, 0.0f);
                Cz[(row0 + j) * (long)ldc + col] = x;
            }
        }
    }
}

// ---------------- GAT1 attention (round-4 verbatim): one wave per (b,h) -----
__global__ __launch_bounds__(256)
void gat1_attn_kernel(float* __restrict__ h1,
                      const int* __restrict__ missing,
                      const float* __restrict__ attl, const float* __restrict__ attr,
                      const float* __restrict__ bias)
{
    const int gtid = blockIdx.x * 256 + threadIdx.x;
    const int wid  = gtid >> 6;
    const int lane = threadIdx.x & 63;
    const int b = wid >> 2;
    const int h = wid & 3;
    const int cb = h * 128 + lane;
    float* base = h1 + (size_t)b * 2048 + cb;

    float hr[4][2];
    #pragma unroll
    for (int j = 0; j < 4; ++j) { hr[j][0] = base[j*512]; hr[j][1] = base[j*512 + 64]; }
    const float al0 = attl[cb], al1 = attl[cb+64];
    const float ar0 = attr[cb], ar1 = attr[cb+64];

    float red[24];
    #pragma unroll
    for (int i = 0; i < 4; ++i)
        #pragma unroll
        for (int j = 0; j < 4; ++j)
            red[i*4+j] = hr[i][0]*hr[j][0] + hr[i][1]*hr[j][1];
    #pragma unroll
    for (int j = 0; j < 4; ++j) {
        red[16+j] = hr[j][0]*al0 + hr[j][1]*al1;
        red[20+j] = hr[j][0]*ar0 + hr[j][1]*ar1;
    }
    #pragma unroll
    for (int m = 1; m < 64; m <<= 1)
        #pragma unroll
        for (int r = 0; r < 24; ++r)
            red[r] += __shfl_xor(red[r], m, 64);

    const int miss = missing[b];
    bool pres[4];
    #pragma unroll
    for (int mm = 0; mm < 4; ++mm) pres[mm] = (miss != mm + 1);

    float attn[4][4];
    #pragma unroll
    for (int i = 0; i < 4; ++i) {
        float av[4]; float mx = -3.4e38f;
        #pragma unroll
        for (int j = 0; j < 4; ++j) {
            const bool mk = (i == j) || (pres[i] && pres[j]);
            float v = (red[20+i] + red[16+j]) * sigmoidf_(red[i*4+j]);
            v = (v >= 0.0f) ? v : 0.2f * v;
            av[j] = mk ? v : -1e30f;
            mx = fmaxf(mx, av[j]);
        }
        float den = 0.0f;
        #pragma unroll
        for (int j = 0; j < 4; ++j) { av[j] = expf(av[j] - mx); den += av[j]; }
        const float inv = 1.0f / den;
        #pragma unroll
        for (int j = 0; j < 4; ++j) attn[i][j] = av[j] * inv;
    }

    const float b0 = bias[cb], b1 = bias[cb+64];
    #pragma unroll
    for (int i = 0; i < 4; ++i) {
        float o0 = b0, o1 = b1;
        #pragma unroll
        for (int j = 0; j < 4; ++j) { o0 += attn[i][j]*hr[j][0]; o1 += attn[i][j]*hr[j][1]; }
        base[i*512]      = gelu_(o0);
        base[i*512 + 64] = gelu_(o1);
    }
}

// ------- GAT2 attention + node-mean pool + LayerNorm (round-4 verbatim) ------
__global__ __launch_bounds__(256)
void gat2_attn_kernel(const float* __restrict__ h2,
                      const int* __restrict__ missing,
                      const float* __restrict__ attl, const float* __restrict__ attr,
                      const float* __restrict__ bias,
                      const float* __restrict__ lng, const float* __restrict__ lnb,
                      float* __restrict__ normed)
{
    const int gtid = blockIdx.x * 256 + threadIdx.x;
    const int b = gtid >> 6;
    const int lane = threadIdx.x & 63;
    const float4* hp = (const float4*)(h2 + (size_t)b * 1024);

    float4 hr[4];
    #pragma unroll
    for (int j = 0; j < 4; ++j) hr[j] = hp[j*64 + lane];
    const float4 al = ((const float4*)attl)[lane];
    const float4 ar = ((const float4*)attr)[lane];

    float red[24];
    #pragma unroll
    for (int i = 0; i < 4; ++i)
        #pragma unroll
        for (int j = 0; j < 4; ++j)
            red[i*4+j] = hr[i].x*hr[j].x + hr[i].y*hr[j].y + hr[i].z*hr[j].z + hr[i].w*hr[j].w;
    #pragma unroll
    for (int j = 0; j < 4; ++j) {
        red[16+j] = hr[j].x*al.x + hr[j].y*al.y + hr[j].z*al.z + hr[j].w*al.w;
        red[20+j] = hr[j].x*ar.x + hr[j].y*ar.y + hr[j].z*ar.z + hr[j].w*ar.w;
    }
    #pragma unroll
    for (int m = 1; m < 64; m <<= 1)
        #pragma unroll
        for (int r = 0; r < 24; ++r)
            red[r] += __shfl_xor(red[r], m, 64);

    const int miss = missing[b];
    bool pres[4];
    #pragma unroll
    for (int mm = 0; mm < 4; ++mm) pres[mm] = (miss != mm + 1);

    float wsum[4] = {0.f, 0.f, 0.f, 0.f};
    #pragma unroll
    for (int i = 0; i < 4; ++i) {
        float av[4]; float mx = -3.4e38f;
        #pragma unroll
        for (int j = 0; j < 4; ++j) {
            const bool mk = (i == j) || (pres[i] && pres[j]);
            float v = (red[20+i] + red[16+j]) * sigmoidf_(red[i*4+j]);
            v = (v >= 0.0f) ? v : 0.2f * v;
            av[j] = mk ? v : -1e30f;
            mx = fmaxf(mx, av[j]);
        }
        float den = 0.0f;
        #pragma unroll
        for (int j = 0; j < 4; ++j) { av[j] = expf(av[j] - mx); den += av[j]; }
        const float inv = 0.25f / den;
        #pragma unroll
        for (int j = 0; j < 4; ++j) wsum[j] += av[j] * inv;
    }

    const float4 bv = ((const float4*)bias)[lane];
    float pooled[4] = {bv.x, bv.y, bv.z, bv.w};
    #pragma unroll
    for (int j = 0; j < 4; ++j) {
        pooled[0] += wsum[j] * hr[j].x;
        pooled[1] += wsum[j] * hr[j].y;
        pooled[2] += wsum[j] * hr[j].z;
        pooled[3] += wsum[j] * hr[j].w;
    }

    float s1 = pooled[0] + pooled[1] + pooled[2] + pooled[3];
    float s2 = pooled[0]*pooled[0] + pooled[1]*pooled[1] + pooled[2]*pooled[2] + pooled[3]*pooled[3];
    #pragma unroll
    for (int m = 1; m < 64; m <<= 1) {
        s1 += __shfl_xor(s1, m, 64);
        s2 += __shfl_xor(s2, m, 64);
    }
    const float mu   = s1 * (1.0f / 256.0f);
    const float var  = s2 * (1.0f / 256.0f) - mu * mu;
    const float rstd = rsqrtf(var + 1e-5f);
    const float4 g  = ((const float4*)lng)[lane];
    const float4 bb = ((const float4*)lnb)[lane];
    float4 o;
    o.x = (pooled[0] - mu) * rstd * g.x + bb.x;
    o.y = (pooled[1] - mu) * rstd * g.y + bb.y;
    o.z = (pooled[2] - mu) * rstd * g.z + bb.z;
    o.w = (pooled[3] - mu) * rstd * g.w + bb.w;
    ((float4*)normed)[(size_t)b * 64 + lane] = o;
}

// ---------------- head2 (round-4 verbatim) ----------------------------------
__global__ __launch_bounds__(256)
void head2_kernel(const float* __restrict__ hid, const float* __restrict__ W2,
                  const float* __restrict__ b2, float* __restrict__ out)
{
    const int t = blockIdx.x * 256 + threadIdx.x;
    const int b = t >> 3, o = t & 7;
    const float4* hp = (const float4*)(hid + (size_t)b * 256);
    const float4* wp = (const float4*)(W2 + o * 256);
    float acc = b2[o];
    #pragma unroll 8
    for (int c = 0; c < 64; ++c) {
        const float4 hv = hp[c], wv = wp[c];
        acc += hv.x*wv.x + hv.y*wv.y + hv.z*wv.z + hv.w*wv.w;
    }
    out[t] = acc;
}

// ---------------- launch (round-4 verbatim) ---------------------------------
extern "C" void kernel_launch(void* const* d_in, const int* in_sizes, int n_in,
                              void* d_out, int out_size, void* d_ws, size_t ws_size,
                              hipStream_t stream)
{
    (void)in_sizes; (void)n_in; (void)out_size; (void)ws_size;
    const float* X0 = (const float*)d_in[0];
    const float* X1 = (const float*)d_in[1];
    const float* X2 = (const float*)d_in[2];
    const float* X3 = (const float*)d_in[3];
    const int*   miss  = (const int*)d_in[4];
    const float* g1_W  = (const float*)d_in[13];
    const float* g1_al = (const float*)d_in[14];
    const float* g1_ar = (const float*)d_in[15];
    const float* g1_b  = (const float*)d_in[16];
    const float* g2_W  = (const float*)d_in[17];
    const float* g2_al = (const float*)d_in[18];
    const float* g2_ar = (const float*)d_in[19];
    const float* g2_b  = (const float*)d_in[20];
    const float* ln_g  = (const float*)d_in[21];
    const float* ln_b  = (const float*)d_in[22];
    const float* h_W1  = (const float*)d_in[23];
    const float* h_b1  = (const float*)d_in[24];
    const float* h_W2  = (const float*)d_in[25];
    const float* h_b2  = (const float*)d_in[26];
    float* out = (float*)d_out;

    // workspace (fp32 elems), round-4 verbatim:
    float* ws     = (float*)d_ws;
    float* feats  = ws;
    float* h1     = ws + 16777216;
    float* h2     = ws;
    float* normed = ws + 16777216;
    float* hid    = normed + 4194304;

    const dim3 blk(256);

    P4 Xs  = {{X0, X1, X2, X3}};
    P4 Wms = {{(const float*)d_in[5], (const float*)d_in[7],
               (const float*)d_in[9], (const float*)d_in[11]}};
    P4 bms = {{(const float*)d_in[6], (const float*)d_in[8],
               (const float*)d_in[10], (const float*)d_in[12]}};
    P4 F4  = {{feats, feats, feats, feats}};
    P4 G1W = {{g1_W, g1_W, g1_W, g1_W}};
    P4 H14 = {{h1, h1, h1, h1}};
    P4 G2W = {{g2_W, g2_W, g2_W, g2_W}};
    P4 N4  = {{normed, normed, normed, normed}};
    P4 HW1 = {{h_W1, h_W1, h_W1, h_W1}};
    P4 HB1 = {{h_b1, h_b1, h_b1, h_b1}};
    P4 NUL = {{nullptr, nullptr, nullptr, nullptr}};

    // 1) per-modality projections (z-batched): feats[B,4,256]
    gemm_nt_mfma<0, true><<<dim3(2, 128, 4), blk, 0, stream>>>(
        Xs, Wms, bms, feats, /*K=*/1024, /*lda=*/1024, /*ldc=*/1024, /*zofs=*/256);

    // 2) gat1 linear: h1[65536,512] = feats[65536,256] @ g1_W^T
    gemm_nt_mfma<0, false><<<dim3(4, 512, 1), blk, 0, stream>>>(
        F4, G1W, NUL, h1, 256, 256, 512, 0);

    // 3) gat1 attention + bias + gelu (in-place on h1)
    gat1_attn_kernel<<<dim3(16384), blk, 0, stream>>>(h1, miss, g1_al, g1_ar, g1_b);

    // 4) gat2 linear: h2[65536,256] = x1[65536,512] @ g2_W^T
    gemm_nt_mfma<0, false><<<dim3(2, 512, 1), blk, 0, stream>>>(
        H14, G2W, NUL, h2, 512, 512, 256, 0);

    // 5) gat2 attention + pool + layernorm -> normed[16384,256]
    gat2_attn_kernel<<<dim3(4096), blk, 0, stream>>>(
        h2, miss, g2_al, g2_ar, g2_b, ln_g, ln_b, normed);

    // 6) head1: hid = relu(normed @ h_W1^T + h_b1)
    gemm_nt_mfma<1, true><<<dim3(2, 128, 1), blk, 0, stream>>>(
        N4, HW1, HB1, hid, 256, 256, 256, 0);

    // 7) head2: out[16384,8]
    head2_kernel<<<dim3(512), blk, 0, stream>>>(hid, h_W2, h_b2, out);
}